// Round 5
// baseline (3356.960 us; speedup 1.0000x reference)
//
#include <hip/hip_runtime.h>
#include <math.h>

// Problem constants
#define NB    1024      // batch rows == scan steps
#define SEQ   600
#define EDIM  300
#define HDIM  256
#define DIN   903       // 3*E + 3
#define GDIM  1024      // 4*H

#define SENT  0xFFFFFFFFu

// ---------------------------------------------------------------------------
// fast transcendentals: v_exp_f32 / v_rcp_f32 (≤2 ulp, verified absmax 0.0)
// ---------------------------------------------------------------------------
__device__ __forceinline__ float fsig(float x) {
    return __builtin_amdgcn_rcpf(1.f + __builtin_amdgcn_exp2f(x * -1.44269504f));
}
__device__ __forceinline__ float ftanh(float x) {
    return 1.f - 2.f * __builtin_amdgcn_rcpf(1.f + __builtin_amdgcn_exp2f(x * 2.88539008f));
}

// 16-lane rotation-reduce on the VALU pipe (no LDS traffic).
__device__ __forceinline__ float row16_sum(float x) {
    x += __int_as_float(__builtin_amdgcn_update_dpp(0, __float_as_int(x), 0x128, 0xf, 0xf, true));
    x += __int_as_float(__builtin_amdgcn_update_dpp(0, __float_as_int(x), 0x124, 0xf, 0xf, true));
    x += __int_as_float(__builtin_amdgcn_update_dpp(0, __float_as_int(x), 0x122, 0xf, 0xf, true));
    x += __int_as_float(__builtin_amdgcn_update_dpp(0, __float_as_int(x), 0x121, 0xf, 0xf, true));
    return x;
}

// Barrier that waits only LDS ops (lgkmcnt), NOT in-flight global stores.
__device__ __forceinline__ void lds_barrier() {
    asm volatile("s_waitcnt lgkmcnt(0)" ::: "memory");
    __builtin_amdgcn_s_barrier();
}

// agent-scope (cross-XCD, via LLC) poll/store — round-3 proven protocol
__device__ __forceinline__ float poll_agent(const float* p) {
    const unsigned* up = (const unsigned*)p;
    unsigned u; int gd = 0;
    do { u = __hip_atomic_load(up, __ATOMIC_RELAXED, __HIP_MEMORY_SCOPE_AGENT); }
    while (u == SENT && ++gd < (1 << 22));
    return __uint_as_float(u);
}
__device__ __forceinline__ void st_agent(float* p, float v) {
    __hip_atomic_store(p, v, __ATOMIC_RELAXED, __HIP_MEMORY_SCOPE_AGENT);
}
// dual store: agent (canonical, LLC — any consumer) THEN volatile (local
// XCD L2 — same-XCD fast consumers). Same value both paths; line ends fresh
// wherever the consumer looks. No correctness dependence on the fast path.
__device__ __forceinline__ void st_dual(float* p, float v) {
    __hip_atomic_store(p, v, __ATOMIC_RELAXED, __HIP_MEMORY_SCOPE_AGENT);
    *(volatile float*)p = v;
}

// ---------------------------------------------------------------------------
// Kernel 1: conv (unchanged)
// ---------------------------------------------------------------------------
__global__ __launch_bounds__(256) void conv_kernel(const int* __restrict__ x,
                                                   const float* __restrict__ emb,
                                                   float* __restrict__ X) {
    const int row = blockIdx.x;
    const int tid = threadIdx.x;
    const int* xr = x + (size_t)row * SEQ;

    __shared__ float seg[3][EDIM];
    __shared__ float scnt[3];
    __shared__ float reds[6];
    __shared__ float coss[3];

    if (tid < 6) reds[tid] = 0.f;
    if (tid < 3) scnt[tid] = 0.f;
    __syncthreads();

    {
        int c0 = 0, c1 = 0, c2 = 0;
        for (int t = tid; t < 200; t += 256) {
            c0 += (xr[t]       != 0);
            c1 += (xr[200 + t] != 0);
            c2 += (xr[400 + t] != 0);
        }
        float f0 = (float)c0, f1 = (float)c1, f2 = (float)c2;
        #pragma unroll
        for (int m = 1; m < 64; m <<= 1) {
            f0 += __shfl_xor(f0, m);
            f1 += __shfl_xor(f1, m);
            f2 += __shfl_xor(f2, m);
        }
        if ((tid & 63) == 0) {
            atomicAdd(&scnt[0], f0);
            atomicAdd(&scnt[1], f1);
            atomicAdd(&scnt[2], f2);
        }
    }
    __syncthreads();

    const float inv0 = 1.f / scnt[0], inv1 = 1.f / scnt[1], inv2 = 1.f / scnt[2];

    for (int d = tid; d < EDIM; d += 256) {
        float a0 = 0.f, a1 = 0.f, a2 = 0.f;
        for (int t = 0; t < 200; t++) {
            a0 += emb[(size_t)xr[t]       * EDIM + d];
            a1 += emb[(size_t)xr[200 + t] * EDIM + d];
            a2 += emb[(size_t)xr[400 + t] * EDIM + d];
        }
        seg[0][d] = a0 * inv0;
        seg[1][d] = a1 * inv1;
        seg[2][d] = a2 * inv2;
    }
    __syncthreads();

    {
        float p0 = 0, p1 = 0, p2 = 0, p3 = 0, p4 = 0, p5 = 0;
        for (int d = tid; d < EDIM; d += 256) {
            float a = seg[0][d], b = seg[1][d], c = seg[2][d];
            p0 += a * a; p1 += b * b; p2 += c * c;
            p3 += a * b; p4 += b * c; p5 += a * c;
        }
        #pragma unroll
        for (int m = 1; m < 64; m <<= 1) {
            p0 += __shfl_xor(p0, m); p1 += __shfl_xor(p1, m);
            p2 += __shfl_xor(p2, m); p3 += __shfl_xor(p3, m);
            p4 += __shfl_xor(p4, m); p5 += __shfl_xor(p5, m);
        }
        if ((tid & 63) == 0) {
            atomicAdd(&reds[0], p0); atomicAdd(&reds[1], p1);
            atomicAdd(&reds[2], p2); atomicAdd(&reds[3], p3);
            atomicAdd(&reds[4], p4); atomicAdd(&reds[5], p5);
        }
    }
    __syncthreads();
    if (tid == 0) {
        float nt = fmaxf(sqrtf(reds[0]), 1e-8f);
        float nu = fmaxf(sqrtf(reds[1]), 1e-8f);
        float nj = fmaxf(sqrtf(reds[2]), 1e-8f);
        coss[0] = reds[3] / (nt * nu);
        coss[1] = reds[4] / (nu * nj);
        coss[2] = reds[5] / (nt * nj);
    }
    __syncthreads();

    float* Xr = X + (size_t)row * DIN;
    for (int col = tid; col < DIN; col += 256) {
        float v;
        if      (col < 300)  v = seg[0][col];
        else if (col == 300) v = coss[0];
        else if (col < 601)  v = seg[1][col - 301];
        else if (col == 601) v = coss[1];
        else if (col < 902)  v = seg[2][col - 602];
        else                 v = coss[2];
        Xr[col] = v;
    }
}

// ---------------------------------------------------------------------------
// Kernel 2: GEMM (unchanged) — G1 = X @ Wih0^T + b_ih0 + b_hh0
// ---------------------------------------------------------------------------
__global__ __launch_bounds__(256) void gemm_bias(const float* __restrict__ A,
                                                 const float* __restrict__ Bm,
                                                 const float* __restrict__ bias1,
                                                 const float* __restrict__ bias2,
                                                 float* __restrict__ C, int K) {
    __shared__ float As[16][68];
    __shared__ float Bs[16][68];
    const int tid = threadIdx.x;
    const int tx = tid & 15, ty = tid >> 4;
    const int m0 = blockIdx.y * 64, n0 = blockIdx.x * 64;

    float acc[4][4] = {};
    for (int k0 = 0; k0 < K; k0 += 16) {
        #pragma unroll
        for (int i = 0; i < 4; i++) {
            int e  = tid + i * 256;
            int rr = e >> 4, kk = e & 15;
            int k  = k0 + kk;
            As[kk][rr] = (k < K) ? A[(size_t)(m0 + rr) * K + k] : 0.f;
            Bs[kk][rr] = (k < K) ? Bm[(size_t)(n0 + rr) * K + k] : 0.f;
        }
        __syncthreads();
        #pragma unroll
        for (int kk = 0; kk < 16; kk++) {
            float a[4], b[4];
            #pragma unroll
            for (int i = 0; i < 4; i++) { a[i] = As[kk][ty * 4 + i]; b[i] = Bs[kk][tx * 4 + i]; }
            #pragma unroll
            for (int i = 0; i < 4; i++)
                #pragma unroll
                for (int j = 0; j < 4; j++)
                    acc[i][j] += a[i] * b[j];
        }
        __syncthreads();
    }
    #pragma unroll
    for (int i = 0; i < 4; i++) {
        int m = m0 + ty * 4 + i;
        #pragma unroll
        for (int j = 0; j < 4; j++) {
            int n = n0 + tx * 4 + j;
            C[(size_t)m * GDIM + n] = acc[i][j] + bias1[n] + bias2[n];
        }
    }
}

// ---------------------------------------------------------------------------
// Kernel 3: fused 2-layer LSTM — round-3 structure + opportunistic XCD-local
// transport. 192 candidate WGs x 512 thr.
// Rendezvous (bounded): count WGs per XCD; first XCD reaching 16 WGs is
// "chosen" (CAS). Chosen-XCD slots 0..15 take recurrence roles with the FAST
// consumer path; 8 other WGs take X-stage; rest exit. On rendezvous timeout:
// blockIdx<24 take round-3 roles, pure agent transport (duplicates are
// value-safe: deterministic identical writes).
// Transport:
//   producers DUAL-store every h replica (agent->LLC AND volatile->local L2)
//   fast consumers: volatile poll (L2 hit ~200cy), guard 8192, STICKY
//     fallback to agent polls for the rest of the run on first exhaustion
//   cross-XCD paths (mailX->X-stage, mailP->L2 recurrence): agent, as round 3
// Compute per step: (4,16) mapping, 4 ds_read_b128, DPP row16 reduce,
// redundant nonlinearity (round-3 verified, absmax 0.0).
// ---------------------------------------------------------------------------
__global__ __launch_bounds__(512) void lstm_fused(
    const float* __restrict__ G1,
    const float* __restrict__ Whh0,
    const float* __restrict__ Wih1,
    const float* __restrict__ Whh1,
    const float* __restrict__ b_ih1,
    const float* __restrict__ b_hh1,
    const float* __restrict__ h0,
    const float* __restrict__ c0,
    unsigned* ctrl,
    float* mailA, float* mailB, float* mailX, float* mailP,
    float* ys2, float* out)
{
    const int tid = threadIdx.x;
    const int l   = tid & 63;
    const int v   = tid >> 6;          // wave 0..7
    const int k   = l >> 4;            // elem within wave (0..3)
    const int q   = l & 15;            // 16-col chunk / role selector

    __shared__ __align__(16) float hb[2][16][20];
    __shared__ int sh_role;
    __shared__ int sh_fast;            // sticky: 1 = volatile fast path OK

    // ---------------- rendezvous (bounded, fail-safe) -----------------------
    if (tid == 0) {
        unsigned xcd;
        asm volatile("s_getreg_b32 %0, hwreg(HW_REG_XCC_ID)" : "=s"(xcd));
        xcd &= 7u;
        unsigned slot = atomicAdd(&ctrl[xcd], 1u);
        if (slot == 15u) atomicCAS(&ctrl[8], 0u, xcd + 1u);
        unsigned ch = 0;
        for (int gd = 0; gd < (1 << 14); gd++) {
            ch = __hip_atomic_load(&ctrl[8], __ATOMIC_RELAXED, __HIP_MEMORY_SCOPE_AGENT);
            if (ch != 0u) break;
        }
        int role = -1, fast = 0;
        if (ch != 0u && xcd == ch - 1u && slot < 16u) {
            role = (int)slot; fast = 1;            // recurrence, same-XCD set
        } else if (ch != 0u) {
            unsigned xs = atomicAdd(&ctrl[9], 1u);
            if (xs < 8u) role = 16 + (int)xs;      // X-stage
        } else {
            if (blockIdx.x < 24) role = blockIdx.x;   // fallback: round-3 mode
        }
        sh_role = role;
        sh_fast = fast;
    }
    __syncthreads();
    const int role = sh_role;
    if (role < 0) return;

    if (role < 16) {
        // ---------------- recurrence WG (L=0: layer1, L=1: layer2) ----------
        const int  L = role >> 3;
        const int  m = role & 7;
        const int  e = m * 32 + 4 * v + k;      // owned element 0..255
        const int  eloc = e & 31;
        const float* Wh = L ? Whh1 : Whh0;
        float* mailH = L ? mailB : mailA;
        const float* mailIn = mailH + (size_t)(m >> 1) * NB * HDIM;  // own replica

        float4 w[4][4];
        #pragma unroll
        for (int g = 0; g < 4; g++)
            #pragma unroll
            for (int j = 0; j < 4; j++)
                w[g][j] = *(const float4*)&Wh[(size_t)(g * 256 + e) * HDIM + q * 16 + j * 4];

        float c = c0[L * HDIM + e];

        for (int t = 0; t < NB; t++) {
            const int nb = t & 1;

            // early G-term issue (one gate row per lane, q<4 only)
            float gq = 0.f;
            unsigned gu = 0;
            const unsigned* gp = nullptr;
            if (q < 4) {
                if (L == 0) {
                    gq = G1[(size_t)t * GDIM + q * 256 + e];
                } else {
                    gp = (const unsigned*)(mailP + ((size_t)m * NB + t) * 128 + q * 32 + eloc);
                    gu = __hip_atomic_load(gp, __ATOMIC_RELAXED, __HIP_MEMORY_SCOPE_AGENT);
                }
            }

            // fill h broadcast (own 32-elem slice was written at t-1 epilogue)
            if (tid < HDIM) {
                if (t == 0) {
                    hb[0][tid >> 4][tid & 15] = h0[L * HDIM + tid];
                } else if ((tid >> 5) != m) {
                    const float* p = mailIn + (size_t)(t - 1) * HDIM + tid;
                    float val;
                    if (sh_fast) {
                        const volatile unsigned* vp = (const volatile unsigned*)p;
                        unsigned u = *vp; int gd = 0;
                        while (u == SENT && ++gd < 8192) u = *vp;
                        if (u == SENT) { sh_fast = 0; val = poll_agent(p); }
                        else val = __uint_as_float(u);
                    } else {
                        val = poll_agent(p);
                    }
                    hb[nb][tid >> 4][tid & 15] = val;
                }
            }
            lds_barrier();

            // matvec: 4 gate rows x 16 cols, h via 4 ds_read_b128
            float a0 = 0.f, a1 = 0.f, a2 = 0.f, a3 = 0.f;
            #pragma unroll
            for (int j = 0; j < 4; j++) {
                float4 hv = *(const float4*)&hb[nb][q][j * 4];
                float4 w0 = w[0][j], w1 = w[1][j], w2 = w[2][j], w3 = w[3][j];
                a0 += hv.x * w0.x + hv.y * w0.y + hv.z * w0.z + hv.w * w0.w;
                a1 += hv.x * w1.x + hv.y * w1.y + hv.z * w1.z + hv.w * w1.w;
                a2 += hv.x * w2.x + hv.y * w2.y + hv.z * w2.z + hv.w * w2.w;
                a3 += hv.x * w3.x + hv.y * w3.y + hv.z * w3.z + hv.w * w3.w;
            }

            if (q < 4) {
                if (L == 1) {
                    int gd = 0;
                    while (gu == SENT && ++gd < (1 << 22))
                        gu = __hip_atomic_load(gp, __ATOMIC_RELAXED, __HIP_MEMORY_SCOPE_AGENT);
                    gq = __uint_as_float(gu);
                }
                if      (q == 0) a0 += gq;
                else if (q == 1) a1 += gq;
                else if (q == 2) a2 += gq;
                else             a3 += gq;
            }

            a0 = row16_sum(a0); a1 = row16_sum(a1);
            a2 = row16_sum(a2); a3 = row16_sum(a3);

            float ig = fsig(a0), fg = fsig(a1), og = fsig(a3);
            c = fg * c + ig * ftanh(a2);
            float h = og * ftanh(c);

            // publish (roles spread across the 16 redundant lanes)
            if (q == 4) hb[nb ^ 1][e >> 4][e & 15] = h;       // own slice, t+1
            if (q == 0) {      // replicas 0,1: agent (LLC) + volatile (L2)
                st_dual(mailH + ((size_t)0 * NB + t) * HDIM + e, h);
                st_dual(mailH + ((size_t)1 * NB + t) * HDIM + e, h);
            }
            if (q == 1) {      // replicas 2,3
                st_dual(mailH + ((size_t)2 * NB + t) * HDIM + e, h);
                st_dual(mailH + ((size_t)3 * NB + t) * HDIM + e, h);
            }
            if (L == 0) {      // cross-XCD: X-stage inputs (agent scope)
                if (q == 2) st_agent(mailX + ((size_t)0 * NB + t) * HDIM + e, h);
                if (q == 3) st_agent(mailX + ((size_t)1 * NB + t) * HDIM + e, h);
            } else {
                if (q == 2) ys2[(size_t)t * HDIM + e] = h;
            }
            if (t == NB - 1 && q == 5) {
                out[1024 + L * HDIM + e] = h;    // hn
                out[1536 + L * HDIM + e] = c;    // cn
            }
        }
    } else {
        // ---------------- X-stage: P2[t] = Wih1·ys1[t] + b_ih1 + b_hh1 ------
        const int n = role - 16;
        const int e = n * 32 + 4 * v + k;
        const int eloc = e & 31;
        const float* xsrc = mailX + (size_t)(n >> 2) * NB * HDIM;

        float4 w[4][4];
        #pragma unroll
        for (int g = 0; g < 4; g++)
            #pragma unroll
            for (int j = 0; j < 4; j++)
                w[g][j] = *(const float4*)&Wih1[(size_t)(g * 256 + e) * HDIM + q * 16 + j * 4];

        float bsum = 0.f;
        if (q < 4) bsum = b_ih1[q * 256 + e] + b_hh1[q * 256 + e];

        for (int t = 0; t < NB; t++) {
            const int nb = t & 1;
            if (tid < HDIM)
                hb[nb][tid >> 4][tid & 15] = poll_agent(xsrc + (size_t)t * HDIM + tid);
            lds_barrier();

            float a0 = 0.f, a1 = 0.f, a2 = 0.f, a3 = 0.f;
            #pragma unroll
            for (int j = 0; j < 4; j++) {
                float4 hv = *(const float4*)&hb[nb][q][j * 4];
                float4 w0 = w[0][j], w1 = w[1][j], w2 = w[2][j], w3 = w[3][j];
                a0 += hv.x * w0.x + hv.y * w0.y + hv.z * w0.z + hv.w * w0.w;
                a1 += hv.x * w1.x + hv.y * w1.y + hv.z * w1.z + hv.w * w1.w;
                a2 += hv.x * w2.x + hv.y * w2.y + hv.z * w2.z + hv.w * w2.w;
                a3 += hv.x * w3.x + hv.y * w3.y + hv.z * w3.z + hv.w * w3.w;
            }
            a0 = row16_sum(a0); a1 = row16_sum(a1);
            a2 = row16_sum(a2); a3 = row16_sum(a3);

            if (q < 4) {
                float pv = (q == 0 ? a0 : q == 1 ? a1 : q == 2 ? a2 : a3) + bsum;
                st_agent(mailP + ((size_t)n * NB + t) * 128 + q * 32 + eloc, pv);
            }
        }
    }
}

// ---------------------------------------------------------------------------
// Kernel 4: fc head (unchanged)
// ---------------------------------------------------------------------------
__global__ __launch_bounds__(256) void fc_kernel(const float* __restrict__ ys2,
                                                 const float* __restrict__ fc_w,
                                                 const float* __restrict__ fc_b,
                                                 float* __restrict__ out) {
    const int row  = blockIdx.x * 4 + (threadIdx.x >> 6);
    const int lane = threadIdx.x & 63;
    float4 y = ((const float4*)(ys2 + (size_t)row * HDIM))[lane];
    float4 wv = ((const float4*)fc_w)[lane];
    float d = y.x * wv.x + y.y * wv.y + y.z * wv.z + y.w * wv.w;
    #pragma unroll
    for (int m = 1; m < 64; m <<= 1) d += __shfl_xor(d, m);
    if (lane == 0) out[row] = 1.f / (1.f + expf(-(d + fc_b[0])));
}

// ---------------------------------------------------------------------------
extern "C" void kernel_launch(void* const* d_in, const int* in_sizes, int n_in,
                              void* d_out, int out_size, void* d_ws, size_t ws_size,
                              hipStream_t stream) {
    const int*   x     = (const int*)  d_in[0];
    const float* h0    = (const float*)d_in[1];
    const float* c0    = (const float*)d_in[2];
    const float* emb   = (const float*)d_in[3];
    const float* w_ih0 = (const float*)d_in[4];
    const float* w_hh0 = (const float*)d_in[5];
    const float* b_ih0 = (const float*)d_in[6];
    const float* b_hh0 = (const float*)d_in[7];
    const float* w_ih1 = (const float*)d_in[8];
    const float* w_hh1 = (const float*)d_in[9];
    const float* b_ih1 = (const float*)d_in[10];
    const float* b_hh1 = (const float*)d_in[11];
    const float* fc_w  = (const float*)d_in[12];
    const float* fc_b  = (const float*)d_in[13];
    float* out = (float*)d_out;

    // workspace layout (floats), ~22.8 MB — no aliasing (mail lines must only
    // ever be touched by the lstm kernel within a run).
    float*    base  = (float*)d_ws;
    unsigned* ctrl  = (unsigned*)d_ws;                 // 10 dwords (1 KB pad)
    float* mailA = base  + 256;                        // 4*NB*HDIM  (4 MB)
    float* mailB = mailA + (size_t)4 * NB * HDIM;      // 4*NB*HDIM  (4 MB)
    float* mailX = mailB + (size_t)4 * NB * HDIM;      // 2*NB*HDIM  (2 MB)
    float* mailP = mailX + (size_t)2 * NB * HDIM;      // 8*NB*128   (4 MB)
    float* G1    = mailP + (size_t)8 * NB * 128;       // NB*GDIM    (4 MB)
    float* ys2   = G1    + (size_t)NB * GDIM;          // NB*HDIM    (1 MB)
    float* X     = ys2   + (size_t)NB * HDIM;          // NB*DIN     (3.7 MB)

    // ctrl zeroed; all mail slots sentinel-filled (0xFFFFFFFF = NaN)
    hipMemsetAsync(ctrl, 0, 1024, stream);
    hipMemsetAsync(mailA, 0xFF, ((size_t)(4 + 4 + 2) * NB * HDIM
                                 + (size_t)8 * NB * 128) * sizeof(float), stream);

    conv_kernel<<<NB, 256, 0, stream>>>(x, emb, X);

    gemm_bias<<<dim3(16, 16), 256, 0, stream>>>(X, w_ih0, b_ih0, b_hh0, G1, DIN);

    lstm_fused<<<192, 512, 0, stream>>>(G1, w_hh0, w_ih1, w_hh1, b_ih1, b_hh1,
                                        h0, c0, ctrl,
                                        mailA, mailB, mailX, mailP, ys2, out);

    fc_kernel<<<NB / 4, 256, 0, stream>>>(ys2, fc_w, fc_b, out);
}